// Round 7
// baseline (247.799 us; speedup 1.0000x reference)
//
#include <hip/hip_runtime.h>

typedef __attribute__((ext_vector_type(8))) short s16x8;
typedef __attribute__((ext_vector_type(4))) float f32x4;
typedef __attribute__((ext_vector_type(2))) float f32x2;

#define F 128

__device__ __forceinline__ unsigned short f2bf(float f) {
    unsigned int u = __float_as_uint(f);
    u = (u + 0x7fffu + ((u >> 16) & 1u)) >> 16;
    return (unsigned short)u;
}
__device__ __forceinline__ float bflo(unsigned int u) { return __uint_as_float(u << 16); }
__device__ __forceinline__ float bfhi(unsigned int u) { return __uint_as_float(u & 0xffff0000u); }
__device__ __forceinline__ float leaky(float x) { return x >= 0.f ? x : 0.2f * x; }
__device__ __forceinline__ float sigmoidf(float x) { return 1.f / (1.f + __expf(-x)); }

// byte-level XOR swizzle (16B granular within a 128B stripe), keyed on row&7
#define SWZ16(row, b) ((b) ^ (((row) & 7) << 4))

// wave-local LDS fence (LDS here is wave-private; no block barrier needed)
#define WAVE_LDS_FENCE() do { \
    asm volatile("s_waitcnt lgkmcnt(0)" ::: "memory"); \
    __builtin_amdgcn_sched_barrier(0); \
} while (0)

// async global->LDS, 16B per lane (wave-uniform LDS base + lane*16)
__device__ __forceinline__ void glds16(void* lds, const void* g) {
    __builtin_amdgcn_global_load_lds(
        (const __attribute__((address_space(1))) unsigned int*)g,
        (__attribute__((address_space(3))) unsigned int*)lds,
        16, 0, 0);
}

// ---------------- kernel 0: transpose + bf16 + pre-swizzle both W ----------------
__global__ __launch_bounds__(256) void prep_w(const float* __restrict__ wRef,
                                              const float* __restrict__ wDir,
                                              unsigned short* __restrict__ wT) {
    int i = blockIdx.x * 256 + threadIdx.x;      // 0..32767
    int m = i >> 14;
    int rr = i & 16383;
    int k = rr >> 7;
    int c = rr & 127;
    const float* W = m ? wDir : wRef;
    wT[m * 16384 + c * 128 + (k ^ (((c & 7) << 3)))] = f2bf(W[k * 128 + c]);
}

// ---------------- fused epilogue: s/t row-dots (f32) + C -> fp8 via wave-local LDS ----------------
__device__ __forceinline__ void epi(const f32x4* acc, unsigned char* cb /*wave-local 4KB bf16*/,
                                    int rowBase, int w, int r, int g, int lane, int N,
                                    const float* __restrict__ aVec,
                                    unsigned char* __restrict__ wh /*fp8, 128B rows*/,
                                    float* __restrict__ sArr, float* __restrict__ tArr) {
    float ps[4] = {0.f, 0.f, 0.f, 0.f}, pt[4] = {0.f, 0.f, 0.f, 0.f};
#pragma unroll
    for (int ct = 0; ct < 8; ++ct) {
        int c = ct * 16 + r;
        float As = aVec[c], At = aVec[128 + c];
#pragma unroll
        for (int q = 0; q < 4; ++q) { ps[q] += acc[ct][q] * As; pt[q] += acc[ct][q] * At; }
    }
#pragma unroll
    for (int off = 1; off <= 8; off <<= 1) {
#pragma unroll
        for (int q = 0; q < 4; ++q) {
            ps[q] += __shfl_xor(ps[q], off);
            pt[q] += __shfl_xor(pt[q], off);
        }
    }
    if (r == 0) {
#pragma unroll
        for (int q = 0; q < 4; ++q) {
            int row = rowBase + w * 16 + g * 4 + q;
            if (row < N) { sArr[row] = ps[q]; tArr[row] = pt[q]; }
        }
    }
    // ---- C -> wave-local LDS (bf16, swizzled) ----
#pragma unroll
    for (int ct = 0; ct < 8; ++ct) {
#pragma unroll
        for (int q = 0; q < 4; ++q) {
            int lrow = g * 4 + q;
            int xb = (ct * 16 + r) * 2;
            *(unsigned short*)(cb + lrow * 256 + SWZ16(lrow, xb)) = f2bf(acc[ct][q]);
        }
    }
    // ---- read back linear (deswizzled) -> fp8 pack -> coalesced 8B stores ----
#pragma unroll
    for (int i = 0; i < 4; ++i) {
        int off = i * 1024 + lane * 16;
        int lrow = off >> 8, x = off & 255;
        uint4 v = *(const uint4*)(cb + lrow * 256 + SWZ16(lrow, x));
        int pk0 = __builtin_amdgcn_cvt_pk_fp8_f32(bflo(v.x), bfhi(v.x), 0, false);
        pk0 = __builtin_amdgcn_cvt_pk_fp8_f32(bflo(v.y), bfhi(v.y), pk0, true);
        int pk1 = __builtin_amdgcn_cvt_pk_fp8_f32(bflo(v.z), bfhi(v.z), 0, false);
        pk1 = __builtin_amdgcn_cvt_pk_fp8_f32(bflo(v.w), bfhi(v.w), pk1, true);
        int grow = rowBase + w * 16 + lrow;
        if (grow < N) *(uint2*)(wh + (size_t)grow * 128 + (x >> 1)) = make_uint2((unsigned)pk0, (unsigned)pk1);
    }
}

// ---------------- kernel 1: MFMA GEMM, both matrices, fused s/t + fp8 Wh ----------------
__global__ __launch_bounds__(256) void gemm_wh(const float* __restrict__ h,
                                               const unsigned short* __restrict__ wT,
                                               const float* __restrict__ aRefG,
                                               const float* __restrict__ aDirG,
                                               unsigned char* __restrict__ whRef,
                                               unsigned char* __restrict__ whDir,
                                               float* __restrict__ sRef, float* __restrict__ tRef,
                                               float* __restrict__ sDir, float* __restrict__ tDir,
                                               int N) {
    __shared__ unsigned char lds[49152];
    const int tid = threadIdx.x;
    const int lane = tid & 63, w = tid >> 6;
    const int r = lane & 15, g = lane >> 4;
    const int rowBase = blockIdx.x * 64;

#pragma unroll
    for (int it = 0; it < 8; ++it) {
        int lin = it * 4096 + tid * 16;
        glds16(lds + 16384 + lin, (const char*)wT + lin);
    }
    float4 av[4][2];
#pragma unroll
    for (int it = 0; it < 4; ++it) {
        int lin = it * 4096 + tid * 16;
        int arow = lin >> 8, x = lin & 255;
        int grow = min(rowBase + arow, N - 1);
        const char* src = (const char*)h + (size_t)grow * 512 + x * 2;
        av[it][0] = *(const float4*)(src);
        av[it][1] = *(const float4*)(src + 16);
    }
#pragma unroll
    for (int it = 0; it < 4; ++it) {
        int lin = it * 4096 + tid * 16;
        int arow = lin >> 8, x = lin & 255;
        s16x8 a;
        a[0] = (short)f2bf(av[it][0].x); a[1] = (short)f2bf(av[it][0].y);
        a[2] = (short)f2bf(av[it][0].z); a[3] = (short)f2bf(av[it][0].w);
        a[4] = (short)f2bf(av[it][1].x); a[5] = (short)f2bf(av[it][1].y);
        a[6] = (short)f2bf(av[it][1].z); a[7] = (short)f2bf(av[it][1].w);
        *(s16x8*)(lds + arow * 256 + SWZ16(arow, x)) = a;
    }
    __syncthreads();

    s16x8 afr[4];
    {
        const int arow = w * 16 + r;
#pragma unroll
        for (int kt = 0; kt < 4; ++kt)
            afr[kt] = *(const s16x8*)(lds + arow * 256 + SWZ16(arow, kt * 64 + g * 16));
    }
    unsigned char* cb = lds + w * 4096;

    {
        f32x4 acc[8];
#pragma unroll
        for (int ct = 0; ct < 8; ++ct) acc[ct] = (f32x4){0.f, 0.f, 0.f, 0.f};
#pragma unroll
        for (int kt = 0; kt < 4; ++kt) {
#pragma unroll
            for (int ct = 0; ct < 8; ++ct) {
                int c = ct * 16 + r;
                s16x8 b = *(const s16x8*)(lds + 16384 + c * 256 + SWZ16(c, kt * 64 + g * 16));
                acc[ct] = __builtin_amdgcn_mfma_f32_16x16x32_bf16(afr[kt], b, acc[ct], 0, 0, 0);
            }
        }
        epi(acc, cb, rowBase, w, r, g, lane, N, aRefG, whRef, sRef, tRef);
    }
    __syncthreads();
#pragma unroll
    for (int it = 0; it < 8; ++it) {
        int lin = it * 4096 + tid * 16;
        glds16(lds + 16384 + lin, (const char*)wT + 32768 + lin);
    }
    __syncthreads();
    {
        f32x4 acc[8];
#pragma unroll
        for (int ct = 0; ct < 8; ++ct) acc[ct] = (f32x4){0.f, 0.f, 0.f, 0.f};
#pragma unroll
        for (int kt = 0; kt < 4; ++kt) {
#pragma unroll
            for (int ct = 0; ct < 8; ++ct) {
                int c = ct * 16 + r;
                s16x8 b = *(const s16x8*)(lds + 16384 + c * 256 + SWZ16(c, kt * 64 + g * 16));
                acc[ct] = __builtin_amdgcn_mfma_f32_16x16x32_bf16(afr[kt], b, acc[ct], 0, 0, 0);
            }
        }
        epi(acc, cb, rowBase, w, r, g, lane, N, aDirG, whDir, sDir, tDir);
    }
}

// ---------------- kernel 2: gather + attention, schedule-pinned pipeline ----------------
// Per wave: idx loads -> t-gathers ISSUED -> [pin] -> compact -> fence ->
// 18 UNCONDITIONAL row loads -> [pin] -> softmax (waits t only, rows in flight) ->
// fence -> coef*row accumulate (coef=0 kills invalid slots). All LDS wave-private.
__device__ __forceinline__ void acc8f8(float* a, uint2 u, float c) {
    f32x2 p0 = __builtin_amdgcn_cvt_pk_f32_fp8((int)u.x, false);
    f32x2 p1 = __builtin_amdgcn_cvt_pk_f32_fp8((int)u.x, true);
    f32x2 p2 = __builtin_amdgcn_cvt_pk_f32_fp8((int)u.y, false);
    f32x2 p3 = __builtin_amdgcn_cvt_pk_f32_fp8((int)u.y, true);
    a[0] += c * p0[0]; a[1] += c * p0[1];
    a[2] += c * p1[0]; a[3] += c * p1[1];
    a[4] += c * p2[0]; a[5] += c * p2[1];
    a[6] += c * p3[0]; a[7] += c * p3[1];
}

__global__ __launch_bounds__(256) void gather_attn(
    const unsigned char* __restrict__ whRef, const unsigned char* __restrict__ whDir,
    const float* __restrict__ sRef, const float* __restrict__ tRef,
    const float* __restrict__ sDir, const float* __restrict__ tDir,
    const int* __restrict__ refNbr, const int* __restrict__ refCnt,
    const int* __restrict__ dirNbr, const int* __restrict__ dirCnt,
    float* __restrict__ out, int N) {
    __shared__ int   s_idx[4][72];    // wave-private: [0..40) compacted ref, [40..72) dir
    __shared__ float s_coef[4][72];

    const int wid = threadIdx.x >> 6;
    const int lane = threadIdx.x & 63;
    const int q = lane >> 4, hl16 = lane & 15;
    const int d = lane >> 4, kk = lane & 15;
    const int n_raw = blockIdx.x * 4 + wid;
    const int n = min(n_raw, N - 1);

    // ---- phase 0: prefill (idx=0 -> safe row-0 fetch; coef=0 -> no contribution) ----
    s_idx[wid][lane] = 0;
    s_coef[wid][lane] = 0.f;
    if (lane < 8) { s_idx[wid][64 + lane] = 0; s_coef[wid][64 + lane] = 0.f; }

    // ---- phase 1: independent loads ----
    int cnt = refCnt[n * 4 + d];                       // <= 10
    int idxR = 0;
    if (kk < 10) idxR = refNbr[(size_t)n * 40 + d * 10 + kk];
    int dcnt = dirCnt[n];
    int idxD = 0;
    if (lane < 32) idxD = dirNbr[(size_t)n * 32 + lane];
    float sR = sRef[n], sD = sDir[n];

    // ---- phase 2: t-gathers, issued BEFORE row loads (pinned) ----
    bool validR = kk < cnt;
    float tv = 0.f, tD = 0.f;
    if (validR) tv = tRef[idxR];
    if (lane < 32 && lane < dcnt) tD = tDir[idxD];
    __builtin_amdgcn_sched_barrier(0);

    // ---- phase 3: compact ref indices; publish dir indices ----
    unsigned long long mask = __ballot(validR);
    int pos = (int)__popcll(mask & ((1ull << lane) - 1ull));
    if (validR) s_idx[wid][pos] = idxR;
    if (lane < 32) s_idx[wid][40 + lane] = idxD;
    WAVE_LDS_FENCE();

    // ---- phase 4: UNCONDITIONAL row loads (18 in flight; pinned here) ----
    uint2 uR[10], uD[8];
#pragma unroll
    for (int j = 0; j < 10; ++j)
        uR[j] = *(const uint2*)(whRef + ((size_t)(unsigned)s_idx[wid][j * 4 + q] << 7) + (hl16 << 3));
#pragma unroll
    for (int j = 0; j < 8; ++j)
        uD[j] = *(const uint2*)(whDir + ((size_t)(unsigned)s_idx[wid][40 + j * 4 + q] << 7) + (hl16 << 3));
    __builtin_amdgcn_sched_barrier(0);

    // ---- phase 5: softmax (vmcnt waits only for t; rows stay outstanding) ----
    float sum = tv;
    sum += __shfl_xor(sum, 1); sum += __shfl_xor(sum, 2);
    sum += __shfl_xor(sum, 4); sum += __shfl_xor(sum, 8);
    float rc = 1.f / (float)max(cnt, 1);
    float e = leaky(sR + sum * rc);
    float mx = fmaxf(e, __shfl_xor(e, 16)); mx = fmaxf(mx, __shfl_xor(mx, 32));
    float wgt = __expf(e - mx);
    float den = wgt + __shfl_xor(wgt, 16); den += __shfl_xor(den, 32);
    if (validR) s_coef[wid][pos] = wgt / den * rc;

    float eD = -1e30f;
    if (lane < 32 && lane < dcnt) eD = leaky(sD + tD);
    float mD = eD;
#pragma unroll
    for (int off = 16; off; off >>= 1) mD = fmaxf(mD, __shfl_xor(mD, off, 32));
    float wD = (lane < dcnt) ? __expf(eD - mD) : 0.f;
    float dD = wD;
#pragma unroll
    for (int off = 16; off; off >>= 1) dD += __shfl_xor(dD, off, 32);
    if (lane < 32 && lane < dcnt) s_coef[wid][40 + lane] = wD / dD;
    WAVE_LDS_FENCE();

    // ---- phase 6: unconditional weighted accumulate (coef 0 for invalid slots) ----
    float accR[8] = {0.f, 0.f, 0.f, 0.f, 0.f, 0.f, 0.f, 0.f};
#pragma unroll
    for (int j = 0; j < 10; ++j) acc8f8(accR, uR[j], s_coef[wid][j * 4 + q]);
    float accD[8] = {0.f, 0.f, 0.f, 0.f, 0.f, 0.f, 0.f, 0.f};
#pragma unroll
    for (int j = 0; j < 8; ++j) acc8f8(accD, uD[j], s_coef[wid][40 + j * 4 + q]);

    // ---- combine quarters + write ----
#pragma unroll
    for (int j = 0; j < 8; ++j) {
        accR[j] += __shfl_xor(accR[j], 16); accR[j] += __shfl_xor(accR[j], 32);
        accD[j] += __shfl_xor(accD[j], 16); accD[j] += __shfl_xor(accD[j], 32);
    }
    if (n_raw < N && q == 0) {
        float o[8];
#pragma unroll
        for (int j = 0; j < 8; ++j) o[j] = 0.5f * (sigmoidf(accR[j]) + sigmoidf(accD[j]));
        float4* dst = (float4*)(out + (size_t)n * F + hl16 * 8);
        dst[0] = make_float4(o[0], o[1], o[2], o[3]);
        dst[1] = make_float4(o[4], o[5], o[6], o[7]);
    }
}

extern "C" void kernel_launch(void* const* d_in, const int* in_sizes, int n_in,
                              void* d_out, int out_size, void* d_ws, size_t ws_size,
                              hipStream_t stream) {
    const float* h    = (const float*)d_in[0];
    const float* Wref = (const float*)d_in[1];
    const float* aRef = (const float*)d_in[2];
    const float* Wdir = (const float*)d_in[3];
    const float* aDir = (const float*)d_in[4];
    const int* refNbr = (const int*)d_in[5];
    const int* refCnt = (const int*)d_in[6];
    const int* dirNbr = (const int*)d_in[7];
    const int* dirCnt = (const int*)d_in[8];
    float* out = (float*)d_out;
    const int N = in_sizes[0] / F;

    const size_t NF = (size_t)N * F;
    unsigned char* whRef = (unsigned char*)d_ws;            // NF fp8
    unsigned char* whDir = whRef + NF;                      // NF fp8
    float* sRef = (float*)(whDir + NF);
    float* tRef = sRef + N;
    float* sDir = tRef + N;
    float* tDir = sDir + N;
    unsigned short* wT = (unsigned short*)(tDir + N);       // 2*128*128 bf16, pre-swizzled

    prep_w<<<128, 256, 0, stream>>>(Wref, Wdir, wT);
    gemm_wh<<<(N + 63) / 64, 256, 0, stream>>>(h, wT, aRef, aDir, whRef, whDir,
                                               sRef, tRef, sDir, tDir, N);
    gather_attn<<<(N + 3) / 4, 256, 0, stream>>>(whRef, whDir, sRef, tRef, sDir, tDir,
                                                 refNbr, refCnt, dirNbr, dirCnt, out, N);
}